// Round 9
// baseline (471.872 us; speedup 1.0000x reference)
//
#include <hip/hip_runtime.h>
#include <stdint.h>

// B=8, T=1024, DIM=2048, H=16, NKV=4, HD=128, G=4
#define T_SEQ 1024

typedef _Float16 f16x8 __attribute__((ext_vector_type(8)));
typedef _Float16 f16x2 __attribute__((ext_vector_type(2)));
typedef float f32x4 __attribute__((ext_vector_type(4)));

typedef __attribute__((address_space(1))) const uint8_t* gptr_t;
typedef __attribute__((address_space(3))) uint8_t* lptr_t;

__device__ __forceinline__ void gload16(const _Float16* g, _Float16* l) {
  // async global->LDS DMA, 16B/lane; LDS dest = wave-uniform base + lane*16
  __builtin_amdgcn_global_load_lds((gptr_t)g, (lptr_t)l, 16, 0, 0);
}

// ---------------- all five fp32->fp16 converts in one kernel ----------------
// wk goes to wkv[0:512], wv to wkv[512:1024] (fused KV weight)
__global__ __launch_bounds__(256) void convert_all(
    const float* __restrict__ x, const float* __restrict__ Wq,
    const float* __restrict__ Wk, const float* __restrict__ Wv,
    const float* __restrict__ Wp, _Float16* __restrict__ xh,
    _Float16* __restrict__ wqh, _Float16* __restrict__ wkh,
    _Float16* __restrict__ wvh, _Float16* __restrict__ wph) {
  int i = blockIdx.x * 256 + threadIdx.x;  // vec8 index, total 3407872
  const float* in;
  _Float16* out;
  int base;
  if (i < 2097152)      { in = x;  out = xh;  base = 0; }
  else if (i < 2621440) { in = Wq; out = wqh; base = 2097152; }
  else if (i < 2752512) { in = Wk; out = wkh; base = 2621440; }
  else if (i < 2883584) { in = Wv; out = wvh; base = 2752512; }
  else                  { in = Wp; out = wph; base = 2883584; }
  int j = i - base;
  const float4* p = (const float4*)in + (size_t)j * 2;
  float4 a = p[0], b = p[1];
  f16x8 o;
  o[0] = (_Float16)a.x; o[1] = (_Float16)a.y; o[2] = (_Float16)a.z; o[3] = (_Float16)a.w;
  o[4] = (_Float16)b.x; o[5] = (_Float16)b.y; o[6] = (_Float16)b.z; o[7] = (_Float16)b.w;
  ((f16x8*)out)[j] = o;
}

// ---------------- 256x256 8-phase f16 MFMA GEMM (T2+T3+T4+T5), K=2048 ----------------
// C = A[M,2048] @ B[N,2048]^T. 512 threads = 8 waves (2Mx4N), wave owns 128x64.
// BK=64; 2 K-tiles per iteration, 8 phases; even tiles -> buf0, odd -> buf1.
// LDS 128 KB -> 1 block/CU (acc=128 VGPR/lane caps occupancy anyway, r7 lesson).
//
// r9 change: ONE barrier per phase (was 2 -> 16/iter). The pre-MFMA barrier is
// removable because waves skew at most 1 phase: a stage in phase P only races
// ds_reads in P-1, so every stage targets a region not read in P or P-1.
// That required moving BOTH B(t2) halves to P4 and BOTH B(t3) halves to P8
// (P4/P8 have no ds_reads). Buffer read phases: buf0-A @P1,P3; buf0-B @P1,P2;
// buf1-A @P5,P7; buf1-B @P5,P6. Stages: A(t1)@P1,P2 (buf1-A, last read prev
// P7 -- its lgkm0 drained those); B(t2)@P4 (buf0-B, read P1,P2); A(t2)@P5,P6
// (buf0-A, read P1,P3); B(t3)@P8 (buf1-B, read P5,P6). All distances >= 2.
// vmcnt gates unchanged: outstanding=12 at P4/P8, vmcnt(4) drains exactly the
// next tile's 8 loads. Rule #18: sched_barrier(0) after each lgkmcnt(0) so the
// compiler can't hoist MFMA above the wait (the removed s_barrier used to pin it).
template <typename OutT>
__global__ __launch_bounds__(512, 2) void gemm256(
    const _Float16* __restrict__ A, const _Float16* __restrict__ B,
    OutT* __restrict__ C0, int ldc0, int nb0,
    OutT* __restrict__ C1, int ldc1, int nbn) {
  __shared__ _Float16 As[2][256][64];
  __shared__ _Float16 Bs[2][256][64];
  const int tid = threadIdx.x;
  const int wave = tid >> 6, lane = tid & 63;
  const int lm = lane & 15, lq = lane >> 4;
  const int wm = wave >> 2, wn = wave & 3;  // 2(M) x 4(N) wave grid

  // T1: XCD-aware bijective swizzle (gridDim.x % 8 == 0)
  const int qx = (int)gridDim.x >> 3;
  const int swz = ((int)blockIdx.x & 7) * qx + ((int)blockIdx.x >> 3);
  const int bm = swz / nbn, bn = swz % nbn;

  const int r8 = lane >> 3;                  // row within 8-row gload slab
  const int csw = ((lane & 7) ^ r8) * 8;     // pre-swizzled source col (f16)
  const _Float16* Asrc = A + (size_t)(bm * 256 + wave * 16 + r8) * 2048 + csw;
  const _Float16* Bsrc = B + (size_t)(bn * 256 + wave * 16 + r8) * 2048 + csw;

  f32x4 acc[8][4];
#pragma unroll
  for (int m = 0; m < 8; m++)
#pragma unroll
    for (int n = 0; n < 4; n++) acc[m][n] = (f32x4){0.f, 0.f, 0.f, 0.f};

  f16x8 af[4][2], bf[4][2];

  auto stageA = [&](int t, int h) {
    const _Float16* s = Asrc + (size_t)h * 128 * 2048 + t * 64;
    _Float16* d = &As[t & 1][h * 128 + wave * 16][0];
    gload16(s, d);
    gload16(s + (size_t)8 * 2048, d + 8 * 64);
  };
  auto stageB = [&](int t, int h) {
    const _Float16* s = Bsrc + (size_t)h * 128 * 2048 + t * 64;
    _Float16* d = &Bs[t & 1][h * 128 + wave * 16][0];
    gload16(s, d);
    gload16(s + (size_t)8 * 2048, d + 8 * 64);
  };
  auto lda = [&](int b, int mh) {
#pragma unroll
    for (int m = 0; m < 4; m++)
#pragma unroll
      for (int ks = 0; ks < 2; ks++)
        af[m][ks] = *(const f16x8*)&As[b][wm * 128 + mh * 64 + m * 16 + lm]
                                      [(((ks * 4 + lq)) ^ (lm & 7)) * 8];
  };
  auto ldb = [&](int b, int nh) {
#pragma unroll
    for (int n = 0; n < 2; n++)
#pragma unroll
      for (int ks = 0; ks < 2; ks++)
        bf[nh * 2 + n][ks] = *(const f16x8*)&Bs[b][wn * 64 + nh * 32 + n * 16 + lm]
                                               [(((ks * 4 + lq)) ^ (lm & 7)) * 8];
  };
  auto mfmaQ = [&](int mh, int nh) {
    __builtin_amdgcn_s_setprio(1);
#pragma unroll
    for (int m = 0; m < 4; m++)
#pragma unroll
      for (int n = 0; n < 2; n++)
#pragma unroll
        for (int ks = 0; ks < 2; ks++)
          acc[mh * 4 + m][nh * 2 + n] = __builtin_amdgcn_mfma_f32_16x16x32_f16(
              af[m][ks], bf[nh * 2 + n][ks], acc[mh * 4 + m][nh * 2 + n], 0, 0, 0);
    __builtin_amdgcn_s_setprio(0);
  };

#define BAR() __builtin_amdgcn_s_barrier()
#define LGKM0()                                      \
  do {                                               \
    asm volatile("s_waitcnt lgkmcnt(0)" ::: "memory"); \
    __builtin_amdgcn_sched_barrier(0);               \
  } while (0)

  // prologue: A(0), B(0), B(1); wait A(0)+B(0) landed (B(1)'s 4 loads may fly)
  stageA(0, 0); stageA(0, 1);
  stageB(0, 0); stageB(0, 1);
  stageB(1, 0); stageB(1, 1);
  asm volatile("s_waitcnt vmcnt(4)" ::: "memory");
  BAR();

  const int NT = 32;  // 2048 / 64
  for (int j = 0; j < NT / 2; ++j) {
    const int t1 = 2 * j + 1, t2 = 2 * j + 2, t3 = 2 * j + 3;
    const bool s2 = t2 < NT, s3 = t3 < NT;
    // ---- K-tile 2j (buf0) ----
    lda(0, 0); ldb(0, 0); stageA(t1, 0);               // P1
    LGKM0(); mfmaQ(0, 0); BAR();
    ldb(0, 1); stageA(t1, 1);                          // P2
    LGKM0(); mfmaQ(0, 1); BAR();
    lda(0, 1);                                         // P3
    LGKM0(); mfmaQ(1, 0); BAR();
    if (s2) { stageB(t2, 0); stageB(t2, 1); }          // P4
    mfmaQ(1, 1);
    if (s2) { asm volatile("s_waitcnt vmcnt(4)" ::: "memory"); }
    else    { asm volatile("s_waitcnt vmcnt(0)" ::: "memory"); }
    BAR();
    // ---- K-tile 2j+1 (buf1) ----
    lda(1, 0); ldb(1, 0); if (s2) stageA(t2, 0);       // P5
    LGKM0(); mfmaQ(0, 0); BAR();
    ldb(1, 1); if (s2) stageA(t2, 1);                  // P6
    LGKM0(); mfmaQ(0, 1); BAR();
    lda(1, 1);                                         // P7
    LGKM0(); mfmaQ(1, 0); BAR();
    if (s3) { stageB(t3, 0); stageB(t3, 1); }          // P8
    mfmaQ(1, 1);
    asm volatile("s_waitcnt vmcnt(4)" ::: "memory");
    BAR();
  }
#undef BAR
#undef LGKM0

  OutT* C;
  int ldc, cb;
  if (bn < nb0) { C = C0; ldc = ldc0; cb = bn * 256; }
  else          { C = C1; ldc = ldc1; cb = (bn - nb0) * 256; }
#pragma unroll
  for (int m = 0; m < 8; m++) {
    size_t gr = (size_t)(bm * 256 + wm * 128 + m * 16 + lq * 4);
#pragma unroll
    for (int n = 0; n < 4; n++) {
      int gc = cb + wn * 64 + n * 16 + lm;
#pragma unroll
      for (int r = 0; r < 4; r++)
        C[(gr + r) * ldc + gc] = (OutT)acc[m][n][r];
    }
  }
}

// ---------------- f16 transpose of V half of kvb: out[512][8192] ----------------
// in = kvb + 512 (row stride 1024); out dense [col][8192]
__global__ __launch_bounds__(256) void transpose16(const _Float16* __restrict__ in,
                                                   _Float16* __restrict__ out) {
  __shared__ _Float16 Ts[64][72];
  int tr = blockIdx.x * 64, tc = blockIdx.y * 64;
  int r0 = threadIdx.x >> 3, c8 = (threadIdx.x & 7) * 8;
#pragma unroll
  for (int i = 0; i < 2; i++) {
    int r = r0 + i * 32;
    *(f16x8*)&Ts[r][c8] = *(const f16x8*)&in[(size_t)(tr + r) * 1024 + tc + c8];
  }
  __syncthreads();
#pragma unroll
  for (int i = 0; i < 2; i++) {
    int oc = r0 + i * 32;
    f16x8 o;
#pragma unroll
    for (int j = 0; j < 8; j++) o[j] = Ts[c8 + j][oc];
    *(f16x8*)&out[(size_t)(tc + oc) * 8192 + tr + c8] = o;
  }
}

// ---------------- RMSNorm + RoPE for Q (with gain) and K, one kernel ----------------
// Q rows = 131072 (bt*16+h, dense 128); K rows = 32768 (bt*4+n, in kvb stride 1024)
// Q gain additionally folds SCALE * log2(e) so attention softmax can use exp2.
__global__ __launch_bounds__(256) void rmsrope_all(_Float16* __restrict__ qh,
                                                   _Float16* __restrict__ kvb,
                                                   const float* __restrict__ gain) {
  int gw = blockIdx.x * 4 + (threadIdx.x >> 6);
  int lane = threadIdx.x & 63;
  _Float16* row;
  int t;
  float g = 1.0f;
  if (gw < 131072) {  // Q: gw = bt*16 + h
    int h = gw & 15;
    t = (gw >> 4) & 1023;
    row = qh + (size_t)gw * 128;
    // fold softmax scale (HD^-0.5) and log2(e) into Q so attn uses exp2
    g = gain[h] * 0.08838834764831845f * 1.4426950408889634f;
  } else {            // K: gk = bt*4 + n -> kvb[bt][n*128..]
    int gk = gw - 131072;
    t = (gk >> 2) & 1023;
    row = kvb + (size_t)(gk >> 2) * 1024 + (gk & 3) * 128;
  }
  float x1 = (float)row[lane], x2 = (float)row[lane + 64];
  float ss = x1 * x1 + x2 * x2;
#pragma unroll
  for (int m = 1; m < 64; m <<= 1) ss += __shfl_xor(ss, m);
  float scale = rsqrtf(ss * (1.0f / 128.0f) + 1e-6f) * g;
  float inv = exp2f((float)lane * -0.2076205059304601f);  // 10000^(-lane/64)
  float ang = (float)t * inv;
  float c = cosf(ang), s = sinf(ang);
  row[lane]      = (_Float16)((x1 * c - x2 * s) * scale);
  row[lane + 64] = (_Float16)((x2 * c + x1 * s) * scale);
}

// ---------------- f16 MFMA flash attention (causal GQA), Q-tile 128 ----------------
// grid (4, H, B) = 512 blocks; block x handles TWO Q-tiles sequentially:
// pass 0 -> qt = 7 - x (long), pass 1 -> qt = x (short); uniform 18 s-iters/block,
// 2 blocks/CU all co-resident. K/V double-buffered (80 KB LDS). T5 setprio on
// both MFMA clusters (r8: part of the -15us attn+vreject gain).
__global__ __launch_bounds__(256, 2) void attn_mfma(const _Float16* __restrict__ q,
                                                    const _Float16* __restrict__ k,
                                                    const _Float16* __restrict__ vT,
                                                    _Float16* __restrict__ y) {
  __shared__ _Float16 Ks[2][4][64][32];    // [buf][d-chunk][s][32] (DMA-staged)
  __shared__ _Float16 VTs[2][2][128][32];  // [buf][s-chunk][d][32] (DMA-staged)
  __shared__ _Float16 Ps[4][32][64];       // per-wave P (32 rows), XOR-swizzled
  int h = blockIdx.y, b = blockIdx.z;
  int kvh = h >> 2;
  int tid = threadIdx.x, wave = tid >> 6, lane = tid & 63;
  int lm = lane & 15, lq = lane >> 4;
  int srow = lane >> 2, scol = (lane & 3) * 8;

  for (int pass = 0; pass < 2; ++pass) {
    int qt = pass ? (int)blockIdx.x : 7 - (int)blockIdx.x;

    // Q fragments: 2 m-tiles x 4 k-chunks, registers
    f16x8 qf[2][4];
#pragma unroll
    for (int mt = 0; mt < 2; mt++) {
      const _Float16* qp =
          q + ((size_t)((b * T_SEQ + qt * 128 + wave * 32 + mt * 16 + lm) * 16 + h)) * 128 +
          lq * 8;
#pragma unroll
      for (int ks = 0; ks < 4; ks++) qf[mt][ks] = *(const f16x8*)(qp + ks * 32);
    }

    f32x4 O[2][8];
#pragma unroll
    for (int mt = 0; mt < 2; mt++)
#pragma unroll
      for (int i = 0; i < 8; i++) O[mt][i] = (f32x4){0.f, 0.f, 0.f, 0.f};
    float mrow[2][4], lrow[2][4];
#pragma unroll
    for (int mt = 0; mt < 2; mt++)
#pragma unroll
      for (int r = 0; r < 4; r++) { mrow[mt][r] = -1e30f; lrow[mt][r] = 0.f; }

    const _Float16* kg =
        k + (size_t)(b * T_SEQ + srow) * 1024 + kvh * 128 + wave * 32 + scol;
    const _Float16* vg =
        vT + (size_t)(kvh * 128 + (wave >> 1) * 64 + srow) * 8192 + b * T_SEQ +
        (wave & 1) * 32 + scol;

    int wrow = qt * 128 + wave * 32;  // wave's first Q row
    int nit = (qt + 1) * 2;           // s-iterations this pass

    // prologue: stage tile 0 into buffer 0
#pragma unroll
    for (int i = 0; i < 4; i++) {
      gload16(kg + (size_t)i * 16 * 1024, &Ks[0][wave][i * 16][0]);
      gload16(vg + (size_t)i * 16 * 8192, &VTs[0][wave & 1][(wave >> 1) * 64 + i * 16][0]);
    }
    kg += (size_t)64 * 1024;
    vg += 64;
    asm volatile("s_waitcnt vmcnt(0)" ::: "memory");
    __builtin_amdgcn_s_barrier();

    for (int it = 0; it < nit; ++it) {
      int cur = it & 1;
      int s0 = it * 64;
      // prefetch next tile into the other buffer (overlaps all compute below)
      if (it + 1 < nit) {
#pragma unroll
        for (int i = 0; i < 4; i++) {
          gload16(kg + (size_t)i * 16 * 1024, &Ks[cur ^ 1][wave][i * 16][0]);
          gload16(vg + (size_t)i * 16 * 8192,
                  &VTs[cur ^ 1][wave & 1][(wave >> 1) * 64 + i * 16][0]);
        }
        kg += (size_t)64 * 1024;
        vg += 64;
      }

      // S = Q K^T
      f32x4 S[2][4];
#pragma unroll
      for (int mt = 0; mt < 2; mt++)
#pragma unroll
        for (int ct = 0; ct < 4; ct++) S[mt][ct] = (f32x4){0.f, 0.f, 0.f, 0.f};
      __builtin_amdgcn_s_setprio(1);
#pragma unroll
      for (int ct = 0; ct < 4; ct++)
#pragma unroll
        for (int ks = 0; ks < 4; ks++) {
          f16x8 bfr = *(const f16x8*)&Ks[cur][ks][ct * 16 + lm][lq * 8];
          S[0][ct] = __builtin_amdgcn_mfma_f32_16x16x32_f16(qf[0][ks], bfr, S[0][ct], 0, 0, 0);
          S[1][ct] = __builtin_amdgcn_mfma_f32_16x16x32_f16(qf[1][ks], bfr, S[1][ct], 0, 0, 0);
        }
      __builtin_amdgcn_s_setprio(0);

      // online softmax (log2 domain)
      float p[2][4][4], al[2][4];
#pragma unroll
      for (int mt = 0; mt < 2; mt++) {
        bool need_mask = (s0 + 63 > wrow + mt * 16);  // wave-uniform
#pragma unroll
        for (int r = 0; r < 4; r++) {
          int grow = wrow + mt * 16 + lq * 4 + r;
          float mx = -1e30f;
#pragma unroll
          for (int ct = 0; ct < 4; ct++) {
            float sv = S[mt][ct][r];
            if (need_mask && (s0 + ct * 16 + lm > grow)) sv = -1e30f;
            p[mt][r][ct] = sv;
            mx = fmaxf(mx, sv);
          }
#pragma unroll
          for (int m = 1; m < 16; m <<= 1) mx = fmaxf(mx, __shfl_xor(mx, m));
          float mn = fmaxf(mrow[mt][r], mx);
          float a = exp2f(mrow[mt][r] - mn);
          mrow[mt][r] = mn;
          float rs = 0.f;
#pragma unroll
          for (int ct = 0; ct < 4; ct++) {
            float pv = exp2f(p[mt][r][ct] - mn);
            p[mt][r][ct] = pv;
            rs += pv;
          }
#pragma unroll
          for (int m = 1; m < 16; m <<= 1) rs += __shfl_xor(rs, m);
          lrow[mt][r] = lrow[mt][r] * a + rs;
          al[mt][r] = a;
        }
      }

      // P -> LDS (XOR-swizzled), rescale O (Ps per-wave: no barrier needed)
#pragma unroll
      for (int mt = 0; mt < 2; mt++)
#pragma unroll
        for (int r = 0; r < 4; r++) {
          int prow = mt * 16 + lq * 4 + r;
#pragma unroll
          for (int ct = 0; ct < 4; ct++) {
            int cg = (ct * 2 + (lm >> 3)) ^ (prow & 7);
            Ps[wave][prow][cg * 8 + (lm & 7)] = (_Float16)p[mt][r][ct];
          }
        }
#pragma unroll
      for (int mt = 0; mt < 2; mt++)
#pragma unroll
        for (int ct = 0; ct < 8; ct++)
#pragma unroll
          for (int r = 0; r < 4; r++) O[mt][ct][r] *= al[mt][r];

      // O += P V
#pragma unroll
      for (int ks2 = 0; ks2 < 2; ks2++) {
        f16x8 afr[2];
#pragma unroll
        for (int mt = 0; mt < 2; mt++) {
          int prow = mt * 16 + lm;
          int cg = (ks2 * 4 + lq) ^ (prow & 7);
          afr[mt] = *(const f16x8*)&Ps[wave][prow][cg * 8];
        }
        __builtin_amdgcn_s_setprio(1);
#pragma unroll
        for (int ct = 0; ct < 8; ct++) {
          f16x8 bfr = *(const f16x8*)&VTs[cur][ks2][ct * 16 + lm][lq * 8];
          O[0][ct] = __builtin_amdgcn_mfma_f32_16x16x32_f16(afr[0], bfr, O[0][ct], 0, 0, 0);
          O[1][ct] = __builtin_amdgcn_mfma_f32_16x16x32_f16(afr[1], bfr, O[1][ct], 0, 0, 0);
        }
        __builtin_amdgcn_s_setprio(0);
      }
      // drain prefetch + guard buffers
      asm volatile("s_waitcnt vmcnt(0)" ::: "memory");
      __builtin_amdgcn_s_barrier();
    }

#pragma unroll
    for (int mt = 0; mt < 2; mt++) {
      float linv[4];
#pragma unroll
      for (int r = 0; r < 4; r++) linv[r] = 1.0f / lrow[mt][r];
      int qrow_base = wrow + mt * 16 + lq * 4;
#pragma unroll
      for (int ct = 0; ct < 8; ct++)
#pragma unroll
        for (int r = 0; r < 4; r++)
          y[((size_t)(b * T_SEQ + qrow_base + r) * 16 + h) * 128 + ct * 16 + lm] =
              (_Float16)(O[mt][ct][r] * linv[r]);
    }
  }
}

// ---------------- v-direction rejection (f16 in/out, packed 4B loads) ----------------
__global__ __launch_bounds__(256) void vreject(const _Float16* __restrict__ y,
                                               const _Float16* __restrict__ kvb,
                                               _Float16* __restrict__ yh) {
  int gw = blockIdx.x * 4 + (threadIdx.x >> 6);  // bt*4 + n
  int lane = threadIdx.x & 63;
  int bt = gw >> 2, n = gw & 3;
  const f16x2* vrow = (const f16x2*)(kvb + (size_t)bt * 1024 + 512 + n * 128);
  f16x2 vv = vrow[lane];
  float v0 = (float)vv[0], v1 = (float)vv[1];
  float ss = v0 * v0 + v1 * v1;
#pragma unroll
  for (int m = 1; m < 64; m <<= 1) ss += __shfl_xor(ss, m);
  float invn = 1.0f / (sqrtf(ss) + 1e-8f);
  float n0 = v0 * invn, n1 = v1 * invn;
  const _Float16* ybase = y + (size_t)bt * 2048 + n * 512;
  _Float16* obase = yh + (size_t)bt * 2048 + n * 512;
#pragma unroll
  for (int g = 0; g < 4; g++) {
    f16x2 yy = ((const f16x2*)(ybase + g * 128))[lane];
    float y0 = (float)yy[0], y1 = (float)yy[1];
    float d = y0 * n0 + y1 * n1;
#pragma unroll
    for (int m = 1; m < 64; m <<= 1) d += __shfl_xor(d, m);
    f16x2 oo;
    oo[0] = (_Float16)(y0 - d * n0);
    oo[1] = (_Float16)(y1 - d * n1);
    ((f16x2*)(obase + g * 128))[lane] = oo;
  }
}

extern "C" void kernel_launch(void* const* d_in, const int* in_sizes, int n_in,
                              void* d_out, int out_size, void* d_ws, size_t ws_size,
                              hipStream_t stream) {
  const float* x    = (const float*)d_in[0];
  const float* Wq   = (const float*)d_in[1];
  const float* Wk   = (const float*)d_in[2];
  const float* Wv   = (const float*)d_in[3];
  const float* Wp   = (const float*)d_in[4];
  const float* gain = (const float*)d_in[5];
  float* out = (float*)d_out;

  // workspace layout (MB offsets)
  char* w = (char*)d_ws;
  _Float16* xh   = (_Float16*)(w + 0);                 // 32 MB
  _Float16* wqh  = (_Float16*)(w + 32u * 1048576);     // 8 MB  (Q weight)
  _Float16* wkvh = (_Float16*)(w + 40u * 1048576);     // 4 MB  (contiguous after wqh ->
                                                       //        fused B [3072][2048])
  _Float16* wph  = (_Float16*)(w + 44u * 1048576);     // 8 MB
  _Float16* qh   = (_Float16*)(w + 52u * 1048576);     // 32 MB
  _Float16* kvb  = (_Float16*)(w + 84u * 1048576);     // 16 MB  [bt][K 512 | V 512]
  _Float16* vTg  = (_Float16*)(w + 100u * 1048576);    // 8 MB   [512][8192]
  _Float16* ya   = (_Float16*)(w + 108u * 1048576);    // 32 MB
  _Float16* yh2  = xh;  // xh dead after QKV GEMM

  // 1) converts -> f16 (Wk into wkvh[0:512], Wv into wkvh[512:1024])
  convert_all<<<13312, 256, 0, stream>>>(x, Wq, Wk, Wv, Wp, xh, wqh,
                                         wkvh, wkvh + (size_t)512 * 2048, wph);

  // 2) fused QKV projection, 256^2 8-phase: B = [wqh;wkvh] N=3072.
  //    Grid 32x12 = 384 blocks (mult of 8). Cols 0..2047 -> qh, 2048..3071 -> kvb.
  gemm256<_Float16><<<384, 512, 0, stream>>>(xh, wqh, qh, 2048, 8, kvb, 1024, 12);

  // 3) V transpose (kvb V half -> vTg [512][8192]); RMSNorm+RoPE on Q and K
  transpose16<<<dim3(128, 8), 256, 0, stream>>>(kvb + 512, vTg);
  rmsrope_all<<<40960, 256, 0, stream>>>(qh, kvb, gain);  // 163840 waves

  // 4) causal GQA MFMA flash attention, balanced dual-qt blocks, dbuf -> ya (f16)
  attn_mfma<<<dim3(4, 16, 8), 256, 0, stream>>>(qh, kvb, vTg, ya);

  // 5) reject v-hat component
  vreject<<<8192, 256, 0, stream>>>(ya, kvb, yh2);

  // 6) output projection (8-phase 256^2, 256 blocks = perfect 1-round packing)
  gemm256<float><<<256, 512, 0, stream>>>(yh2, wph, out, 2048, 8,
                                          (float*)nullptr, 2048, 8);
}

// Round 10
// 459.008 us; speedup vs baseline: 1.0280x; 1.0280x over previous
//
#include <hip/hip_runtime.h>
#include <stdint.h>

// B=8, T=1024, DIM=2048, H=16, NKV=4, HD=128, G=4
#define T_SEQ 1024

typedef _Float16 f16x8 __attribute__((ext_vector_type(8)));
typedef _Float16 f16x2 __attribute__((ext_vector_type(2)));
typedef float f32x4 __attribute__((ext_vector_type(4)));

typedef __attribute__((address_space(1))) const uint8_t* gptr_t;
typedef __attribute__((address_space(3))) uint8_t* lptr_t;

__device__ __forceinline__ void gload16(const _Float16* g, _Float16* l) {
  // async global->LDS DMA, 16B/lane; LDS dest = wave-uniform base + lane*16
  __builtin_amdgcn_global_load_lds((gptr_t)g, (lptr_t)l, 16, 0, 0);
}

// ---------------- all five fp32->fp16 converts in one kernel ----------------
// wk goes to wkv[0:512], wv to wkv[512:1024] (fused KV weight)
__global__ __launch_bounds__(256) void convert_all(
    const float* __restrict__ x, const float* __restrict__ Wq,
    const float* __restrict__ Wk, const float* __restrict__ Wv,
    const float* __restrict__ Wp, _Float16* __restrict__ xh,
    _Float16* __restrict__ wqh, _Float16* __restrict__ wkh,
    _Float16* __restrict__ wvh, _Float16* __restrict__ wph) {
  int i = blockIdx.x * 256 + threadIdx.x;  // vec8 index, total 3407872
  const float* in;
  _Float16* out;
  int base;
  if (i < 2097152)      { in = x;  out = xh;  base = 0; }
  else if (i < 2621440) { in = Wq; out = wqh; base = 2097152; }
  else if (i < 2752512) { in = Wk; out = wkh; base = 2621440; }
  else if (i < 2883584) { in = Wv; out = wvh; base = 2752512; }
  else                  { in = Wp; out = wph; base = 2883584; }
  int j = i - base;
  const float4* p = (const float4*)in + (size_t)j * 2;
  float4 a = p[0], b = p[1];
  f16x8 o;
  o[0] = (_Float16)a.x; o[1] = (_Float16)a.y; o[2] = (_Float16)a.z; o[3] = (_Float16)a.w;
  o[4] = (_Float16)b.x; o[5] = (_Float16)b.y; o[6] = (_Float16)b.z; o[7] = (_Float16)b.w;
  ((f16x8*)out)[j] = o;
}

// ---------------- 256x256 4-window f16 MFMA GEMM (T2+T3+T4+T5), K=2048 ----------------
// C = A[M,2048] @ B[N,2048]^T. 512 threads = 8 waves (2Mx4N), wave owns 128x64.
// BK=64; 2 K-tiles per iteration; even tiles -> buf0, odd -> buf1. LDS 128 KB.
//
// r10: 4 barriers/iter (was 8), NO forced lgkmcnt before MFMA (compiler inserts
// precise counted lgkm waits for the compiler-visible ds_reads; the old manual
// lgkmcnt(0)+sched_barrier only removed scheduling freedom). Windows:
//   W1 = {lda0,ldb0,ldb1,lda1-reads of buf_a + stage A(t1) + Q00,Q01,Q10}
//   W2 = {stage B(t2) + Q11 + vmcnt gate}
//   W3 = {same for buf_b tile + stage A(t2)}   W4 = {stage B(t3) + Q11 + gate}
// Cross-wave hazard audit (stage vs read, barrier distance): A(t1)@W1 vs buf1
// reads@W3 (2 bars); B(t2)@W2 vs buf0-B reads@W1 (1 bar); A(t2)@W3 vs buf0-A
// reads@W1 (2 bars); B(t3)@W4 vs buf1-B reads@W3 (1 bar). Requirement: no wave
// crosses a read-window's closing barrier with reads in flight -> hardware
// lgkmcnt(0) AT W1/W3-end barriers (after the MFMAs: nearly free).
// vmcnt invariant at both gates: survived 4 + issued 8 = 12 -> vmcnt(4) drains
// exactly the next tile's 8 loads. Last iter: W2 gate vmcnt(0) (no t2 stage).
template <typename OutT>
__global__ __launch_bounds__(512, 2) void gemm256(
    const _Float16* __restrict__ A, const _Float16* __restrict__ B,
    OutT* __restrict__ C0, int ldc0, int nb0,
    OutT* __restrict__ C1, int ldc1, int nbn) {
  __shared__ _Float16 As[2][256][64];
  __shared__ _Float16 Bs[2][256][64];
  const int tid = threadIdx.x;
  const int wave = tid >> 6, lane = tid & 63;
  const int lm = lane & 15, lq = lane >> 4;
  const int wm = wave >> 2, wn = wave & 3;  // 2(M) x 4(N) wave grid

  // T1: XCD-aware bijective swizzle (gridDim.x % 8 == 0)
  const int qx = (int)gridDim.x >> 3;
  const int swz = ((int)blockIdx.x & 7) * qx + ((int)blockIdx.x >> 3);
  const int bm = swz / nbn, bn = swz % nbn;

  const int r8 = lane >> 3;                  // row within 8-row gload slab
  const int csw = ((lane & 7) ^ r8) * 8;     // pre-swizzled source col (f16)
  const _Float16* Asrc = A + (size_t)(bm * 256 + wave * 16 + r8) * 2048 + csw;
  const _Float16* Bsrc = B + (size_t)(bn * 256 + wave * 16 + r8) * 2048 + csw;

  f32x4 acc[8][4];
#pragma unroll
  for (int m = 0; m < 8; m++)
#pragma unroll
    for (int n = 0; n < 4; n++) acc[m][n] = (f32x4){0.f, 0.f, 0.f, 0.f};

  f16x8 af[4][2], bf[4][2];

  auto stageA = [&](int t, int h) {
    const _Float16* s = Asrc + (size_t)h * 128 * 2048 + t * 64;
    _Float16* d = &As[t & 1][h * 128 + wave * 16][0];
    gload16(s, d);
    gload16(s + (size_t)8 * 2048, d + 8 * 64);
  };
  auto stageB = [&](int t, int h) {
    const _Float16* s = Bsrc + (size_t)h * 128 * 2048 + t * 64;
    _Float16* d = &Bs[t & 1][h * 128 + wave * 16][0];
    gload16(s, d);
    gload16(s + (size_t)8 * 2048, d + 8 * 64);
  };
  auto lda = [&](int b, int mh) {
#pragma unroll
    for (int m = 0; m < 4; m++)
#pragma unroll
      for (int ks = 0; ks < 2; ks++)
        af[m][ks] = *(const f16x8*)&As[b][wm * 128 + mh * 64 + m * 16 + lm]
                                      [(((ks * 4 + lq)) ^ (lm & 7)) * 8];
  };
  auto ldb = [&](int b, int nh) {
#pragma unroll
    for (int n = 0; n < 2; n++)
#pragma unroll
      for (int ks = 0; ks < 2; ks++)
        bf[nh * 2 + n][ks] = *(const f16x8*)&Bs[b][wn * 64 + nh * 32 + n * 16 + lm]
                                               [(((ks * 4 + lq)) ^ (lm & 7)) * 8];
  };
  auto mfmaQ = [&](int mh, int nh) {
    __builtin_amdgcn_s_setprio(1);
#pragma unroll
    for (int m = 0; m < 4; m++)
#pragma unroll
      for (int n = 0; n < 2; n++)
#pragma unroll
        for (int ks = 0; ks < 2; ks++)
          acc[mh * 4 + m][nh * 2 + n] = __builtin_amdgcn_mfma_f32_16x16x32_f16(
              af[m][ks], bf[nh * 2 + n][ks], acc[mh * 4 + m][nh * 2 + n], 0, 0, 0);
    __builtin_amdgcn_s_setprio(0);
  };

#define BAR() __builtin_amdgcn_s_barrier()
#define BARX()                                         \
  do {                                                 \
    asm volatile("s_waitcnt lgkmcnt(0)" ::: "memory"); \
    __builtin_amdgcn_s_barrier();                      \
  } while (0)

  // prologue: A(0), B(0), B(1); wait A(0)+B(0) landed (B(1)'s 4 loads may fly)
  stageA(0, 0); stageA(0, 1);
  stageB(0, 0); stageB(0, 1);
  stageB(1, 0); stageB(1, 1);
  asm volatile("s_waitcnt vmcnt(4)" ::: "memory");
  BAR();

  const int NT = 32;  // 2048 / 64
  for (int j = 0; j < NT / 2; ++j) {
    const int t1 = 2 * j + 1, t2 = 2 * j + 2, t3 = 2 * j + 3;
    const bool s2 = t2 < NT, s3 = t3 < NT;
    // ---- W1: K-tile 2j (buf0) Q00,Q01,Q10; stage A(t1) ----
    lda(0, 0); ldb(0, 0); stageA(t1, 0);
    mfmaQ(0, 0);
    ldb(0, 1); stageA(t1, 1);
    mfmaQ(0, 1);
    lda(0, 1);
    mfmaQ(1, 0);
    BARX();
    // ---- W2: Q11; stage B(t2); gate ----
    if (s2) { stageB(t2, 0); stageB(t2, 1); }
    mfmaQ(1, 1);
    if (s2) { asm volatile("s_waitcnt vmcnt(4)" ::: "memory"); }
    else    { asm volatile("s_waitcnt vmcnt(0)" ::: "memory"); }
    BAR();
    // ---- W3: K-tile 2j+1 (buf1) Q00,Q01,Q10; stage A(t2) ----
    lda(1, 0); ldb(1, 0); if (s2) stageA(t2, 0);
    mfmaQ(0, 0);
    ldb(1, 1); if (s2) stageA(t2, 1);
    mfmaQ(0, 1);
    lda(1, 1);
    mfmaQ(1, 0);
    BARX();
    // ---- W4: Q11; stage B(t3); gate ----
    if (s3) { stageB(t3, 0); stageB(t3, 1); }
    mfmaQ(1, 1);
    asm volatile("s_waitcnt vmcnt(4)" ::: "memory");
    BAR();
  }
#undef BAR
#undef BARX

  OutT* C;
  int ldc, cb;
  if (bn < nb0) { C = C0; ldc = ldc0; cb = bn * 256; }
  else          { C = C1; ldc = ldc1; cb = (bn - nb0) * 256; }
#pragma unroll
  for (int m = 0; m < 8; m++) {
    size_t gr = (size_t)(bm * 256 + wm * 128 + m * 16 + lq * 4);
#pragma unroll
    for (int n = 0; n < 4; n++) {
      int gc = cb + wn * 64 + n * 16 + lm;
#pragma unroll
      for (int r = 0; r < 4; r++)
        C[(gr + r) * ldc + gc] = (OutT)acc[m][n][r];
    }
  }
}

// ---------------- f16 transpose of V half of kvb: out[512][8192] ----------------
// in = kvb + 512 (row stride 1024); out dense [col][8192]
__global__ __launch_bounds__(256) void transpose16(const _Float16* __restrict__ in,
                                                   _Float16* __restrict__ out) {
  __shared__ _Float16 Ts[64][72];
  int tr = blockIdx.x * 64, tc = blockIdx.y * 64;
  int r0 = threadIdx.x >> 3, c8 = (threadIdx.x & 7) * 8;
#pragma unroll
  for (int i = 0; i < 2; i++) {
    int r = r0 + i * 32;
    *(f16x8*)&Ts[r][c8] = *(const f16x8*)&in[(size_t)(tr + r) * 1024 + tc + c8];
  }
  __syncthreads();
#pragma unroll
  for (int i = 0; i < 2; i++) {
    int oc = r0 + i * 32;
    f16x8 o;
#pragma unroll
    for (int j = 0; j < 8; j++) o[j] = Ts[c8 + j][oc];
    *(f16x8*)&out[(size_t)(tc + oc) * 8192 + tr + c8] = o;
  }
}

// ---------------- RMSNorm + RoPE for Q (with gain) and K, one kernel ----------------
// Q rows = 131072 (bt*16+h, dense 128); K rows = 32768 (bt*4+n, in kvb stride 1024)
// Q gain additionally folds SCALE * log2(e) so attention softmax can use exp2.
__global__ __launch_bounds__(256) void rmsrope_all(_Float16* __restrict__ qh,
                                                   _Float16* __restrict__ kvb,
                                                   const float* __restrict__ gain) {
  int gw = blockIdx.x * 4 + (threadIdx.x >> 6);
  int lane = threadIdx.x & 63;
  _Float16* row;
  int t;
  float g = 1.0f;
  if (gw < 131072) {  // Q: gw = bt*16 + h
    int h = gw & 15;
    t = (gw >> 4) & 1023;
    row = qh + (size_t)gw * 128;
    // fold softmax scale (HD^-0.5) and log2(e) into Q so attn uses exp2
    g = gain[h] * 0.08838834764831845f * 1.4426950408889634f;
  } else {            // K: gk = bt*4 + n -> kvb[bt][n*128..]
    int gk = gw - 131072;
    t = (gk >> 2) & 1023;
    row = kvb + (size_t)(gk >> 2) * 1024 + (gk & 3) * 128;
  }
  float x1 = (float)row[lane], x2 = (float)row[lane + 64];
  float ss = x1 * x1 + x2 * x2;
#pragma unroll
  for (int m = 1; m < 64; m <<= 1) ss += __shfl_xor(ss, m);
  float scale = rsqrtf(ss * (1.0f / 128.0f) + 1e-6f) * g;
  float inv = exp2f((float)lane * -0.2076205059304601f);  // 10000^(-lane/64)
  float ang = (float)t * inv;
  float c = cosf(ang), s = sinf(ang);
  row[lane]      = (_Float16)((x1 * c - x2 * s) * scale);
  row[lane + 64] = (_Float16)((x2 * c + x1 * s) * scale);
}

// ---------------- f16 MFMA flash attention (causal GQA), Q-tile 128 ----------------
// grid (4, H, B) = 512 blocks; block x handles TWO Q-tiles sequentially:
// pass 0 -> qt = 7 - x (long), pass 1 -> qt = x (short); uniform 18 s-iters/block,
// 2 blocks/CU all co-resident. K/V double-buffered (80 KB LDS). T5 setprio on
// both MFMA clusters (r8: part of the -15us attn+vreject gain).
__global__ __launch_bounds__(256, 2) void attn_mfma(const _Float16* __restrict__ q,
                                                    const _Float16* __restrict__ k,
                                                    const _Float16* __restrict__ vT,
                                                    _Float16* __restrict__ y) {
  __shared__ _Float16 Ks[2][4][64][32];    // [buf][d-chunk][s][32] (DMA-staged)
  __shared__ _Float16 VTs[2][2][128][32];  // [buf][s-chunk][d][32] (DMA-staged)
  __shared__ _Float16 Ps[4][32][64];       // per-wave P (32 rows), XOR-swizzled
  int h = blockIdx.y, b = blockIdx.z;
  int kvh = h >> 2;
  int tid = threadIdx.x, wave = tid >> 6, lane = tid & 63;
  int lm = lane & 15, lq = lane >> 4;
  int srow = lane >> 2, scol = (lane & 3) * 8;

  for (int pass = 0; pass < 2; ++pass) {
    int qt = pass ? (int)blockIdx.x : 7 - (int)blockIdx.x;

    // Q fragments: 2 m-tiles x 4 k-chunks, registers
    f16x8 qf[2][4];
#pragma unroll
    for (int mt = 0; mt < 2; mt++) {
      const _Float16* qp =
          q + ((size_t)((b * T_SEQ + qt * 128 + wave * 32 + mt * 16 + lm) * 16 + h)) * 128 +
          lq * 8;
#pragma unroll
      for (int ks = 0; ks < 4; ks++) qf[mt][ks] = *(const f16x8*)(qp + ks * 32);
    }

    f32x4 O[2][8];
#pragma unroll
    for (int mt = 0; mt < 2; mt++)
#pragma unroll
      for (int i = 0; i < 8; i++) O[mt][i] = (f32x4){0.f, 0.f, 0.f, 0.f};
    float mrow[2][4], lrow[2][4];
#pragma unroll
    for (int mt = 0; mt < 2; mt++)
#pragma unroll
      for (int r = 0; r < 4; r++) { mrow[mt][r] = -1e30f; lrow[mt][r] = 0.f; }

    const _Float16* kg =
        k + (size_t)(b * T_SEQ + srow) * 1024 + kvh * 128 + wave * 32 + scol;
    const _Float16* vg =
        vT + (size_t)(kvh * 128 + (wave >> 1) * 64 + srow) * 8192 + b * T_SEQ +
        (wave & 1) * 32 + scol;

    int wrow = qt * 128 + wave * 32;  // wave's first Q row
    int nit = (qt + 1) * 2;           // s-iterations this pass

    // prologue: stage tile 0 into buffer 0
#pragma unroll
    for (int i = 0; i < 4; i++) {
      gload16(kg + (size_t)i * 16 * 1024, &Ks[0][wave][i * 16][0]);
      gload16(vg + (size_t)i * 16 * 8192, &VTs[0][wave & 1][(wave >> 1) * 64 + i * 16][0]);
    }
    kg += (size_t)64 * 1024;
    vg += 64;
    asm volatile("s_waitcnt vmcnt(0)" ::: "memory");
    __builtin_amdgcn_s_barrier();

    for (int it = 0; it < nit; ++it) {
      int cur = it & 1;
      int s0 = it * 64;
      // prefetch next tile into the other buffer (overlaps all compute below)
      if (it + 1 < nit) {
#pragma unroll
        for (int i = 0; i < 4; i++) {
          gload16(kg + (size_t)i * 16 * 1024, &Ks[cur ^ 1][wave][i * 16][0]);
          gload16(vg + (size_t)i * 16 * 8192,
                  &VTs[cur ^ 1][wave & 1][(wave >> 1) * 64 + i * 16][0]);
        }
        kg += (size_t)64 * 1024;
        vg += 64;
      }

      // S = Q K^T
      f32x4 S[2][4];
#pragma unroll
      for (int mt = 0; mt < 2; mt++)
#pragma unroll
        for (int ct = 0; ct < 4; ct++) S[mt][ct] = (f32x4){0.f, 0.f, 0.f, 0.f};
      __builtin_amdgcn_s_setprio(1);
#pragma unroll
      for (int ct = 0; ct < 4; ct++)
#pragma unroll
        for (int ks = 0; ks < 4; ks++) {
          f16x8 bfr = *(const f16x8*)&Ks[cur][ks][ct * 16 + lm][lq * 8];
          S[0][ct] = __builtin_amdgcn_mfma_f32_16x16x32_f16(qf[0][ks], bfr, S[0][ct], 0, 0, 0);
          S[1][ct] = __builtin_amdgcn_mfma_f32_16x16x32_f16(qf[1][ks], bfr, S[1][ct], 0, 0, 0);
        }
      __builtin_amdgcn_s_setprio(0);

      // online softmax (log2 domain)
      float p[2][4][4], al[2][4];
#pragma unroll
      for (int mt = 0; mt < 2; mt++) {
        bool need_mask = (s0 + 63 > wrow + mt * 16);  // wave-uniform
#pragma unroll
        for (int r = 0; r < 4; r++) {
          int grow = wrow + mt * 16 + lq * 4 + r;
          float mx = -1e30f;
#pragma unroll
          for (int ct = 0; ct < 4; ct++) {
            float sv = S[mt][ct][r];
            if (need_mask && (s0 + ct * 16 + lm > grow)) sv = -1e30f;
            p[mt][r][ct] = sv;
            mx = fmaxf(mx, sv);
          }
#pragma unroll
          for (int m = 1; m < 16; m <<= 1) mx = fmaxf(mx, __shfl_xor(mx, m));
          float mn = fmaxf(mrow[mt][r], mx);
          float a = exp2f(mrow[mt][r] - mn);
          mrow[mt][r] = mn;
          float rs = 0.f;
#pragma unroll
          for (int ct = 0; ct < 4; ct++) {
            float pv = exp2f(p[mt][r][ct] - mn);
            p[mt][r][ct] = pv;
            rs += pv;
          }
#pragma unroll
          for (int m = 1; m < 16; m <<= 1) rs += __shfl_xor(rs, m);
          lrow[mt][r] = lrow[mt][r] * a + rs;
          al[mt][r] = a;
        }
      }

      // P -> LDS (XOR-swizzled), rescale O (Ps per-wave: no barrier needed)
#pragma unroll
      for (int mt = 0; mt < 2; mt++)
#pragma unroll
        for (int r = 0; r < 4; r++) {
          int prow = mt * 16 + lq * 4 + r;
#pragma unroll
          for (int ct = 0; ct < 4; ct++) {
            int cg = (ct * 2 + (lm >> 3)) ^ (prow & 7);
            Ps[wave][prow][cg * 8 + (lm & 7)] = (_Float16)p[mt][r][ct];
          }
        }
#pragma unroll
      for (int mt = 0; mt < 2; mt++)
#pragma unroll
        for (int ct = 0; ct < 8; ct++)
#pragma unroll
          for (int r = 0; r < 4; r++) O[mt][ct][r] *= al[mt][r];

      // O += P V
#pragma unroll
      for (int ks2 = 0; ks2 < 2; ks2++) {
        f16x8 afr[2];
#pragma unroll
        for (int mt = 0; mt < 2; mt++) {
          int prow = mt * 16 + lm;
          int cg = (ks2 * 4 + lq) ^ (prow & 7);
          afr[mt] = *(const f16x8*)&Ps[wave][prow][cg * 8];
        }
        __builtin_amdgcn_s_setprio(1);
#pragma unroll
        for (int ct = 0; ct < 8; ct++) {
          f16x8 bfr = *(const f16x8*)&VTs[cur][ks2][ct * 16 + lm][lq * 8];
          O[0][ct] = __builtin_amdgcn_mfma_f32_16x16x32_f16(afr[0], bfr, O[0][ct], 0, 0, 0);
          O[1][ct] = __builtin_amdgcn_mfma_f32_16x16x32_f16(afr[1], bfr, O[1][ct], 0, 0, 0);
        }
        __builtin_amdgcn_s_setprio(0);
      }
      // drain prefetch + guard buffers
      asm volatile("s_waitcnt vmcnt(0)" ::: "memory");
      __builtin_amdgcn_s_barrier();
    }

#pragma unroll
    for (int mt = 0; mt < 2; mt++) {
      float linv[4];
#pragma unroll
      for (int r = 0; r < 4; r++) linv[r] = 1.0f / lrow[mt][r];
      int qrow_base = wrow + mt * 16 + lq * 4;
#pragma unroll
      for (int ct = 0; ct < 8; ct++)
#pragma unroll
        for (int r = 0; r < 4; r++)
          y[((size_t)(b * T_SEQ + qrow_base + r) * 16 + h) * 128 + ct * 16 + lm] =
              (_Float16)(O[mt][ct][r] * linv[r]);
    }
  }
}

// ---------------- v-direction rejection (f16 in/out, packed 4B loads) ----------------
__global__ __launch_bounds__(256) void vreject(const _Float16* __restrict__ y,
                                               const _Float16* __restrict__ kvb,
                                               _Float16* __restrict__ yh) {
  int gw = blockIdx.x * 4 + (threadIdx.x >> 6);  // bt*4 + n
  int lane = threadIdx.x & 63;
  int bt = gw >> 2, n = gw & 3;
  const f16x2* vrow = (const f16x2*)(kvb + (size_t)bt * 1024 + 512 + n * 128);
  f16x2 vv = vrow[lane];
  float v0 = (float)vv[0], v1 = (float)vv[1];
  float ss = v0 * v0 + v1 * v1;
#pragma unroll
  for (int m = 1; m < 64; m <<= 1) ss += __shfl_xor(ss, m);
  float invn = 1.0f / (sqrtf(ss) + 1e-8f);
  float n0 = v0 * invn, n1 = v1 * invn;
  const _Float16* ybase = y + (size_t)bt * 2048 + n * 512;
  _Float16* obase = yh + (size_t)bt * 2048 + n * 512;
#pragma unroll
  for (int g = 0; g < 4; g++) {
    f16x2 yy = ((const f16x2*)(ybase + g * 128))[lane];
    float y0 = (float)yy[0], y1 = (float)yy[1];
    float d = y0 * n0 + y1 * n1;
#pragma unroll
    for (int m = 1; m < 64; m <<= 1) d += __shfl_xor(d, m);
    f16x2 oo;
    oo[0] = (_Float16)(y0 - d * n0);
    oo[1] = (_Float16)(y1 - d * n1);
    ((f16x2*)(obase + g * 128))[lane] = oo;
  }
}

extern "C" void kernel_launch(void* const* d_in, const int* in_sizes, int n_in,
                              void* d_out, int out_size, void* d_ws, size_t ws_size,
                              hipStream_t stream) {
  const float* x    = (const float*)d_in[0];
  const float* Wq   = (const float*)d_in[1];
  const float* Wk   = (const float*)d_in[2];
  const float* Wv   = (const float*)d_in[3];
  const float* Wp   = (const float*)d_in[4];
  const float* gain = (const float*)d_in[5];
  float* out = (float*)d_out;

  // workspace layout (MB offsets)
  char* w = (char*)d_ws;
  _Float16* xh   = (_Float16*)(w + 0);                 // 32 MB
  _Float16* wqh  = (_Float16*)(w + 32u * 1048576);     // 8 MB  (Q weight)
  _Float16* wkvh = (_Float16*)(w + 40u * 1048576);     // 4 MB  (contiguous after wqh ->
                                                       //        fused B [3072][2048])
  _Float16* wph  = (_Float16*)(w + 44u * 1048576);     // 8 MB
  _Float16* qh   = (_Float16*)(w + 52u * 1048576);     // 32 MB
  _Float16* kvb  = (_Float16*)(w + 84u * 1048576);     // 16 MB  [bt][K 512 | V 512]
  _Float16* vTg  = (_Float16*)(w + 100u * 1048576);    // 8 MB   [512][8192]
  _Float16* ya   = (_Float16*)(w + 108u * 1048576);    // 32 MB
  _Float16* yh2  = xh;  // xh dead after QKV GEMM

  // 1) converts -> f16 (Wk into wkvh[0:512], Wv into wkvh[512:1024])
  convert_all<<<13312, 256, 0, stream>>>(x, Wq, Wk, Wv, Wp, xh, wqh,
                                         wkvh, wkvh + (size_t)512 * 2048, wph);

  // 2) fused QKV projection, 256^2 4-window: B = [wqh;wkvh] N=3072.
  //    Grid 32x12 = 384 blocks (mult of 8). Cols 0..2047 -> qh, 2048..3071 -> kvb.
  gemm256<_Float16><<<384, 512, 0, stream>>>(xh, wqh, qh, 2048, 8, kvb, 1024, 12);

  // 3) V transpose (kvb V half -> vTg [512][8192]); RMSNorm+RoPE on Q and K
  transpose16<<<dim3(128, 8), 256, 0, stream>>>(kvb + 512, vTg);
  rmsrope_all<<<40960, 256, 0, stream>>>(qh, kvb, gain);  // 163840 waves

  // 4) causal GQA MFMA flash attention, balanced dual-qt blocks, dbuf -> ya (f16)
  attn_mfma<<<dim3(4, 16, 8), 256, 0, stream>>>(qh, kvb, vTg, ya);

  // 5) reject v-hat component
  vreject<<<8192, 256, 0, stream>>>(ya, kvb, yh2);

  // 6) output projection (4-window 256^2, 256 blocks = perfect 1-round packing)
  gemm256<float><<<256, 512, 0, stream>>>(yh2, wph, out, 2048, 8,
                                          (float*)nullptr, 2048, 8);
}